// Round 1
// baseline (153.103 us; speedup 1.0000x reference)
//
#include <hip/hip_runtime.h>

#define IS2 0.7071067811865476f
#define C3F 0.35355339059327373f   // (1/sqrt(2))^3
#define TAU_F 0.05f

// ------------------------------------------------------------------
// 2D multilevel Haar (8x8), matches reference _haar2_fwd / _haar2_inv
// ------------------------------------------------------------------
__device__ __forceinline__ void haar2_fwd(float (&m)[64]) {
    float t[64];
    #pragma unroll
    for (int half = 4; half >= 1; half >>= 1) {
        const int sz = half * 2;
        // rows (axis -2)
        #pragma unroll
        for (int r = 0; r < half; ++r)
            #pragma unroll
            for (int c = 0; c < sz; ++c) {
                float a = m[(2*r)*8 + c], b = m[(2*r+1)*8 + c];
                t[r*8 + c]        = (a + b) * IS2;
                t[(r+half)*8 + c] = (a - b) * IS2;
            }
        #pragma unroll
        for (int r = 0; r < sz; ++r)
            #pragma unroll
            for (int c = 0; c < sz; ++c) m[r*8+c] = t[r*8+c];
        // cols (axis -1)
        #pragma unroll
        for (int r = 0; r < sz; ++r)
            #pragma unroll
            for (int c = 0; c < half; ++c) {
                float a = m[r*8 + 2*c], b = m[r*8 + 2*c + 1];
                t[r*8 + c]        = (a + b) * IS2;
                t[r*8 + c + half] = (a - b) * IS2;
            }
        #pragma unroll
        for (int r = 0; r < sz; ++r)
            #pragma unroll
            for (int c = 0; c < sz; ++c) m[r*8+c] = t[r*8+c];
    }
}

__device__ __forceinline__ void haar2_inv(float (&m)[64]) {
    float t[64];
    #pragma unroll
    for (int sz = 2; sz <= 8; sz <<= 1) {
        const int half = sz >> 1;
        // cols first (axis -1)
        #pragma unroll
        for (int r = 0; r < sz; ++r)
            #pragma unroll
            for (int c = 0; c < half; ++c) {
                float lo = m[r*8 + c], hi = m[r*8 + c + half];
                t[r*8 + 2*c]     = (lo + hi) * IS2;
                t[r*8 + 2*c + 1] = (lo - hi) * IS2;
            }
        #pragma unroll
        for (int r = 0; r < sz; ++r)
            #pragma unroll
            for (int c = 0; c < sz; ++c) m[r*8+c] = t[r*8+c];
        // rows (axis -2)
        #pragma unroll
        for (int r = 0; r < half; ++r)
            #pragma unroll
            for (int c = 0; c < sz; ++c) {
                float lo = m[r*8 + c], hi = m[(r+half)*8 + c];
                t[(2*r)*8 + c]   = (lo + hi) * IS2;
                t[(2*r+1)*8 + c] = (lo - hi) * IS2;
            }
        #pragma unroll
        for (int r = 0; r < sz; ++r)
            #pragma unroll
            for (int c = 0; c < sz; ++c) m[r*8+c] = t[r*8+c];
    }
}

// ------------------------------------------------------------------
// Forward 3D Haar level: in (B, 2S,2S,2S) -> 8 bands each (B,S,S,S),
// band-major layout, band stride B*S^3.
//   band[bd,bh,bw] = c3 * sum_e (-1)^(b.e) x[e]
// ------------------------------------------------------------------
template<int S, int B>
__global__ __launch_bounds__(256) void dwt3_fwd(const float* __restrict__ in,
                                                float* __restrict__ out) {
    const int tid = blockIdx.x * blockDim.x + threadIdx.x;
    constexpr int total = B * S * S * S;
    if (tid >= total) return;
    const int w = tid % S;
    const int h = (tid / S) % S;
    const int d = (tid / (S*S)) % S;
    const int b = tid / (S*S*S);
    constexpr int IS = 2 * S;
    const float* p = in + (((size_t)b * IS + 2*d) * IS + 2*h) * IS + 2*w;

    float2 q00 = *(const float2*)(p);                         // ed=0, eh=0
    float2 q01 = *(const float2*)(p + IS);                    // ed=0, eh=1
    float2 q10 = *(const float2*)(p + (size_t)IS*IS);         // ed=1, eh=0
    float2 q11 = *(const float2*)(p + (size_t)IS*IS + IS);    // ed=1, eh=1

    // W butterfly: wl/wh [ed][eh]
    float wl00 = q00.x + q00.y, wh00 = q00.x - q00.y;
    float wl01 = q01.x + q01.y, wh01 = q01.x - q01.y;
    float wl10 = q10.x + q10.y, wh10 = q10.x - q10.y;
    float wl11 = q11.x + q11.y, wh11 = q11.x - q11.y;
    // H butterfly: [ed][bw]
    float hl0l = wl00 + wl01, hh0l = wl00 - wl01;
    float hl0h = wh00 + wh01, hh0h = wh00 - wh01;
    float hl1l = wl10 + wl11, hh1l = wl10 - wl11;
    float hl1h = wh10 + wh11, hh1h = wh10 - wh11;
    // D butterfly -> bands, band id = bd*4 + bh*2 + bw
    constexpr size_t bs_ = (size_t)B * S * S * S;
    const size_t o = (size_t)tid;
    out[0*bs_ + o] = (hl0l + hl1l) * C3F;  // lll
    out[1*bs_ + o] = (hl0h + hl1h) * C3F;  // llh
    out[2*bs_ + o] = (hh0l + hh1l) * C3F;  // lhl
    out[3*bs_ + o] = (hh0h + hh1h) * C3F;  // lhh
    out[4*bs_ + o] = (hl0l - hl1l) * C3F;  // hll
    out[5*bs_ + o] = (hl0h - hl1h) * C3F;  // hlh
    out[6*bs_ + o] = (hh0l - hh1l) * C3F;  // hhl
    out[7*bs_ + o] = (hh0h - hh1h) * C3F;  // hhh
}

// ------------------------------------------------------------------
// Inverse 3D Haar level: 8 bands (B,S,S,S) -> out (B,2S,2S,2S)
//   x[e] = c3 * sum_b (-1)^(b.e) band[b]
// ------------------------------------------------------------------
template<int S, int B>
__global__ __launch_bounds__(256) void dwt3_inv(const float* __restrict__ bands,
                                                float* __restrict__ out) {
    const int tid = blockIdx.x * blockDim.x + threadIdx.x;
    constexpr int total = B * S * S * S;
    if (tid >= total) return;
    const int w = tid % S;
    const int h = (tid / S) % S;
    const int d = (tid / (S*S)) % S;
    const int b = tid / (S*S*S);
    constexpr size_t bs_ = (size_t)B * S * S * S;
    const size_t o = (size_t)tid;

    float b0 = bands[0*bs_+o], b1 = bands[1*bs_+o], b2 = bands[2*bs_+o], b3 = bands[3*bs_+o];
    float b4 = bands[4*bs_+o], b5 = bands[5*bs_+o], b6 = bands[6*bs_+o], b7 = bands[7*bs_+o];
    // D butterfly
    float c0 = b0 + b4, c1 = b1 + b5, c2 = b2 + b6, c3 = b3 + b7;   // ed=0
    float c4 = b0 - b4, c5 = b1 - b5, c6 = b2 - b6, c7 = b3 - b7;   // ed=1
    // H butterfly: e[ed][eh][bw]
    float e00 = c0 + c2, e01 = c1 + c3;   // ed=0, eh=0
    float e02 = c0 - c2, e03 = c1 - c3;   // ed=0, eh=1
    float e10 = c4 + c6, e11 = c5 + c7;   // ed=1, eh=0
    float e12 = c4 - c6, e13 = c5 - c7;   // ed=1, eh=1
    // W butterfly + store
    constexpr int IS = 2 * S;
    float* p = out + (((size_t)b * IS + 2*d) * IS + 2*h) * IS + 2*w;
    *(float2*)(p)                        = make_float2((e00+e01)*C3F, (e00-e01)*C3F);
    *(float2*)(p + IS)                   = make_float2((e02+e03)*C3F, (e02-e03)*C3F);
    *(float2*)(p + (size_t)IS*IS)        = make_float2((e10+e11)*C3F, (e10-e11)*C3F);
    *(float2*)(p + (size_t)IS*IS + IS)   = make_float2((e12+e13)*C3F, (e12-e13)*C3F);
}

// ------------------------------------------------------------------
// Bandlet block processing, in-place over 7 bands.
// One 64-thread wave handles 8 blocks of 8x8x8.
// LDS storage pos for block element (i,j,k): nb*520 + i*64 + j*8 + ((k+i+j)&7)
//   -> exactly 2-way bank aliasing for all three normal access patterns (free).
// Per normal phase: thread t handles block nb=t>>3, slice s=t&7 :
//   n=0: M[r][c] = blk[s][r][c]   (slice axis = block-D)
//   n=1: M[r][c] = blk[r][s][c]   (slice axis = block-H)
//   n=2: M[r][c] = blk[r][c][s]   (slice axis = block-W)
// fwd -> soft-threshold (keep M[0][0]) -> inv -> accumulate; final /3.
// ------------------------------------------------------------------
template<int NRM>
__device__ __forceinline__ void process_normal(const float* __restrict__ inb,
                                               float* __restrict__ accb, int s) {
    float m[64];
    #pragma unroll
    for (int r = 0; r < 8; ++r)
        #pragma unroll
        for (int c = 0; c < 8; ++c) {
            int pos;
            if (NRM == 0)      pos = (s << 6) + (r << 3) + ((c + s + r) & 7);
            else if (NRM == 1) pos = (r << 6) + (s << 3) + ((c + r + s) & 7);
            else               pos = (r << 6) + (c << 3) + ((s + r + c) & 7);
            m[r*8 + c] = inb[pos];
        }
    haar2_fwd(m);
    float dc = m[0];
    #pragma unroll
    for (int e = 0; e < 64; ++e) {
        float v = m[e];
        float av = fabsf(v) - TAU_F;
        m[e] = av > 0.0f ? copysignf(av, v) : 0.0f;
    }
    m[0] = dc;
    haar2_inv(m);
    #pragma unroll
    for (int r = 0; r < 8; ++r)
        #pragma unroll
        for (int c = 0; c < 8; ++c) {
            int pos;
            if (NRM == 0)      pos = (s << 6) + (r << 3) + ((c + s + r) & 7);
            else if (NRM == 1) pos = (r << 6) + (s << 3) + ((c + r + s) & 7);
            else               pos = (r << 6) + (c << 3) + ((s + r + c) & 7);
            accb[pos] += m[r*8 + c];
        }
}

template<int S, int B>
__global__ __launch_bounds__(64) void blockproc(float* __restrict__ bands) {
    constexpr int ND  = S / 8;
    constexpr int BPB = B * ND * ND * ND;    // blocks per band
    constexpr int TOTAL = 7 * BPB;
    constexpr int LST = 520;                  // block stride in LDS floats (520%32==8)
    __shared__ float lin[8 * LST];
    __shared__ float lacc[8 * LST];

    const int t  = threadIdx.x;
    const int wg = blockIdx.x;
    const int j  = t >> 3;
    const int kk = t & 7;

    // Per-block global base pointers (uniform across the wave)
    float* bp[8];
    #pragma unroll
    for (int nb = 0; nb < 8; ++nb) {
        const int bid = wg * 8 + nb;
        if (bid < TOTAL) {
            const int band = bid / BPB;
            const int r0 = bid - band * BPB;
            const int bb = r0 / (ND*ND*ND);
            const int r1 = r0 - bb * (ND*ND*ND);
            const int di = r1 / (ND*ND);
            const int r2 = r1 - di * (ND*ND);
            const int hi = r2 / ND;
            const int wi = r2 - hi * ND;
            bp[nb] = bands + (size_t)band * ((size_t)B*S*S*S) + (size_t)bb * (S*S*S)
                     + (size_t)(8*di) * (S*S) + (8*hi) * S + (8*wi);
        } else {
            bp[nb] = nullptr;
        }
    }

    // Load blocks into LDS (swizzled) + zero accumulators
    #pragma unroll
    for (int nb = 0; nb < 8; ++nb) {
        #pragma unroll
        for (int q = 0; q < 8; ++q) lacc[nb*LST + q*64 + t] = 0.0f;
        if (bp[nb]) {
            #pragma unroll
            for (int q = 0; q < 8; ++q) {
                const int k = (kk - q - j) & 7;     // inverse of storage swizzle
                lin[nb*LST + q*64 + t] = bp[nb][q*(S*S) + j*S + k];
            }
        }
    }
    __syncthreads();

    const int nb = t >> 3;
    const int s  = t & 7;
    const bool valid = (wg * 8 + nb) < TOTAL;
    const float* inb  = &lin[nb * LST];
    float*       accb = &lacc[nb * LST];

    if (valid) process_normal<0>(inb, accb, s);
    __syncthreads();
    if (valid) process_normal<1>(inb, accb, s);
    __syncthreads();
    if (valid) process_normal<2>(inb, accb, s);
    __syncthreads();

    // Write back (in place), scaled by 1/3
    #pragma unroll
    for (int nb2 = 0; nb2 < 8; ++nb2) {
        if (bp[nb2]) {
            #pragma unroll
            for (int q = 0; q < 8; ++q) {
                const int k = (kk - q - j) & 7;
                bp[nb2][q*(S*S) + j*S + k] = lacc[nb2*LST + q*64 + t] * (1.0f/3.0f);
            }
        }
    }
}

// ------------------------------------------------------------------
// Pipeline:
//   x (2,1,160^3) --fwd--> bands1[8](2,80^3)            [d_ws, 32.77 MB]
//   bands1[0]     --fwd--> bands2[8](2,40^3)            [staged in d_out, 4.1 MB]
//   blockproc bands1[1..7] in-place
//   blockproc bands2[1..7] in-place
//   bands2        --inv--> bands1[0]  (2,80^3)
//   bands1        --inv--> d_out (2,160^3)  (overwrites bands2 staging)
// ------------------------------------------------------------------
extern "C" void kernel_launch(void* const* d_in, const int* in_sizes, int n_in,
                              void* d_out, int out_size, void* d_ws, size_t ws_size,
                              hipStream_t stream) {
    const float* x = (const float*)d_in[0];
    float* out = (float*)d_out;
    float* bands1 = (float*)d_ws;                 // 8 * 2*80^3 floats
    float* bands2 = (float*)d_out;                // 8 * 2*40^3 floats (dead space until final inverse)

    constexpr int B = 2;  // B*C = 2*1
    constexpr size_t B1S = (size_t)B * 80 * 80 * 80;   // band stride level 1
    constexpr size_t B2S = (size_t)B * 40 * 40 * 40;   // band stride level 2

    // forward level 1: 160^3 -> 8 x 80^3
    dwt3_fwd<80, B><<<(B*80*80*80) / 256, 256, 0, stream>>>(x, bands1);
    // forward level 2: lll (80^3) -> 8 x 40^3
    dwt3_fwd<40, B><<<(B*40*40*40) / 256, 256, 0, stream>>>(bands1, bands2);
    // block processing, bands 1..7 of each level (in place)
    blockproc<80, B><<<(7*B*10*10*10 + 7) / 8, 64, 0, stream>>>(bands1 + B1S);
    blockproc<40, B><<<(7*B*5*5*5   + 7) / 8, 64, 0, stream>>>(bands2 + B2S);
    // inverse level 2 -> replaces lll of level 1
    dwt3_inv<40, B><<<(B*40*40*40) / 256, 256, 0, stream>>>(bands2, bands1);
    // inverse level 1 -> final output
    dwt3_inv<80, B><<<(B*80*80*80) / 256, 256, 0, stream>>>(bands1, out);
}

// Round 2
// 119.204 us; speedup vs baseline: 1.2844x; 1.2844x over previous
//
#include <hip/hip_runtime.h>

#define IS2 0.7071067811865476f
#define C3F 0.35355339059327373f   // (1/sqrt(2))^3
#define TAU_F 0.05f

// ------------------------------------------------------------------
// 2D multilevel Haar (8x8), matches reference _haar2_fwd / _haar2_inv
// ------------------------------------------------------------------
__device__ __forceinline__ void haar2_fwd(float (&m)[64]) {
    float t[64];
    #pragma unroll
    for (int half = 4; half >= 1; half >>= 1) {
        const int sz = half * 2;
        #pragma unroll
        for (int r = 0; r < half; ++r)
            #pragma unroll
            for (int c = 0; c < sz; ++c) {
                float a = m[(2*r)*8 + c], b = m[(2*r+1)*8 + c];
                t[r*8 + c]        = (a + b) * IS2;
                t[(r+half)*8 + c] = (a - b) * IS2;
            }
        #pragma unroll
        for (int r = 0; r < sz; ++r)
            #pragma unroll
            for (int c = 0; c < sz; ++c) m[r*8+c] = t[r*8+c];
        #pragma unroll
        for (int r = 0; r < sz; ++r)
            #pragma unroll
            for (int c = 0; c < half; ++c) {
                float a = m[r*8 + 2*c], b = m[r*8 + 2*c + 1];
                t[r*8 + c]        = (a + b) * IS2;
                t[r*8 + c + half] = (a - b) * IS2;
            }
        #pragma unroll
        for (int r = 0; r < sz; ++r)
            #pragma unroll
            for (int c = 0; c < sz; ++c) m[r*8+c] = t[r*8+c];
    }
}

__device__ __forceinline__ void haar2_inv(float (&m)[64]) {
    float t[64];
    #pragma unroll
    for (int sz = 2; sz <= 8; sz <<= 1) {
        const int half = sz >> 1;
        #pragma unroll
        for (int r = 0; r < sz; ++r)
            #pragma unroll
            for (int c = 0; c < half; ++c) {
                float lo = m[r*8 + c], hi = m[r*8 + c + half];
                t[r*8 + 2*c]     = (lo + hi) * IS2;
                t[r*8 + 2*c + 1] = (lo - hi) * IS2;
            }
        #pragma unroll
        for (int r = 0; r < sz; ++r)
            #pragma unroll
            for (int c = 0; c < sz; ++c) m[r*8+c] = t[r*8+c];
        #pragma unroll
        for (int r = 0; r < half; ++r)
            #pragma unroll
            for (int c = 0; c < sz; ++c) {
                float lo = m[r*8 + c], hi = m[(r+half)*8 + c];
                t[(2*r)*8 + c]   = (lo + hi) * IS2;
                t[(2*r+1)*8 + c] = (lo - hi) * IS2;
            }
        #pragma unroll
        for (int r = 0; r < sz; ++r)
            #pragma unroll
            for (int c = 0; c < sz; ++c) m[r*8+c] = t[r*8+c];
    }
}

// fwd -> soft-threshold (keep DC) -> inv on one 8x8 slice, in registers
__device__ __forceinline__ void bandlet_slice(float (&m)[64]) {
    haar2_fwd(m);
    float dc = m[0];
    #pragma unroll
    for (int e = 0; e < 64; ++e) {
        float v = m[e];
        float av = fabsf(v) - TAU_F;
        m[e] = av > 0.0f ? copysignf(av, v) : 0.0f;
    }
    m[0] = dc;
    haar2_inv(m);
}

// ------------------------------------------------------------------
// Forward 3D Haar level: in (B, 2S,2S,2S) -> 8 bands each (B,S,S,S)
// ------------------------------------------------------------------
template<int S, int B>
__global__ __launch_bounds__(256) void dwt3_fwd(const float* __restrict__ in,
                                                float* __restrict__ out) {
    const int tid = blockIdx.x * blockDim.x + threadIdx.x;
    constexpr int total = B * S * S * S;
    if (tid >= total) return;
    const int w = tid % S;
    const int h = (tid / S) % S;
    const int d = (tid / (S*S)) % S;
    const int b = tid / (S*S*S);
    constexpr int IS = 2 * S;
    const float* p = in + (((size_t)b * IS + 2*d) * IS + 2*h) * IS + 2*w;

    float2 q00 = *(const float2*)(p);
    float2 q01 = *(const float2*)(p + IS);
    float2 q10 = *(const float2*)(p + (size_t)IS*IS);
    float2 q11 = *(const float2*)(p + (size_t)IS*IS + IS);

    float wl00 = q00.x + q00.y, wh00 = q00.x - q00.y;
    float wl01 = q01.x + q01.y, wh01 = q01.x - q01.y;
    float wl10 = q10.x + q10.y, wh10 = q10.x - q10.y;
    float wl11 = q11.x + q11.y, wh11 = q11.x - q11.y;
    float hl0l = wl00 + wl01, hh0l = wl00 - wl01;
    float hl0h = wh00 + wh01, hh0h = wh00 - wh01;
    float hl1l = wl10 + wl11, hh1l = wl10 - wl11;
    float hl1h = wh10 + wh11, hh1h = wh10 - wh11;
    constexpr size_t bs_ = (size_t)B * S * S * S;
    const size_t o = (size_t)tid;
    out[0*bs_ + o] = (hl0l + hl1l) * C3F;
    out[1*bs_ + o] = (hl0h + hl1h) * C3F;
    out[2*bs_ + o] = (hh0l + hh1l) * C3F;
    out[3*bs_ + o] = (hh0h + hh1h) * C3F;
    out[4*bs_ + o] = (hl0l - hl1l) * C3F;
    out[5*bs_ + o] = (hl0h - hl1h) * C3F;
    out[6*bs_ + o] = (hh0l - hh1l) * C3F;
    out[7*bs_ + o] = (hh0h - hh1h) * C3F;
}

// ------------------------------------------------------------------
// Inverse 3D Haar level: 8 bands (B,S,S,S) -> out (B,2S,2S,2S)
// ------------------------------------------------------------------
template<int S, int B>
__global__ __launch_bounds__(256) void dwt3_inv(const float* __restrict__ bands,
                                                float* __restrict__ out) {
    const int tid = blockIdx.x * blockDim.x + threadIdx.x;
    constexpr int total = B * S * S * S;
    if (tid >= total) return;
    const int w = tid % S;
    const int h = (tid / S) % S;
    const int d = (tid / (S*S)) % S;
    const int b = tid / (S*S*S);
    constexpr size_t bs_ = (size_t)B * S * S * S;
    const size_t o = (size_t)tid;

    float b0 = bands[0*bs_+o], b1 = bands[1*bs_+o], b2 = bands[2*bs_+o], b3 = bands[3*bs_+o];
    float b4 = bands[4*bs_+o], b5 = bands[5*bs_+o], b6 = bands[6*bs_+o], b7 = bands[7*bs_+o];
    float c0 = b0 + b4, c1 = b1 + b5, c2 = b2 + b6, c3 = b3 + b7;
    float c4 = b0 - b4, c5 = b1 - b5, c6 = b2 - b6, c7 = b3 - b7;
    float e00 = c0 + c2, e01 = c1 + c3;
    float e02 = c0 - c2, e03 = c1 - c3;
    float e10 = c4 + c6, e11 = c5 + c7;
    float e12 = c4 - c6, e13 = c5 - c7;
    constexpr int IS = 2 * S;
    float* p = out + (((size_t)b * IS + 2*d) * IS + 2*h) * IS + 2*w;
    *(float2*)(p)                        = make_float2((e00+e01)*C3F, (e00-e01)*C3F);
    *(float2*)(p + IS)                   = make_float2((e02+e03)*C3F, (e02-e03)*C3F);
    *(float2*)(p + (size_t)IS*IS)        = make_float2((e10+e11)*C3F, (e10-e11)*C3F);
    *(float2*)(p + (size_t)IS*IS + IS)   = make_float2((e12+e13)*C3F, (e12-e13)*C3F);
}

// ------------------------------------------------------------------
// Bandlet block processing, both levels merged into one dispatch.
// One 64-thread wave = 8 blocks of 8x8x8. ONE LDS buffer per block
// (516 dwords, bank-balanced for all b128 patterns); accumulator in
// registers (thread owns output slice d=s of its block nb=t>>3).
//
// Phases (single wave per wg -> barriers are just lgkmcnt drains):
//   stage-in -> N0 gather+transform into a (no exchange needed)
//   N2 gather (strided b32) + transform -> g      [held in regs]
//   N1 gather (b128 rows)               -> w      [raw, held]
//   scatter g (R2) back to plain positions (lin now dead)
//   transform w -> R1 ; read R2 rows -> a += ; write R1 rows ;
//   read R1 rows -> a += ; stage-out a/3.
// ------------------------------------------------------------------
__global__ __launch_bounds__(64, 2) void blockproc2(float* __restrict__ b1,
                                                    float* __restrict__ b2) {
    constexpr int LST = 516;   // 516 % 32 == 4 -> all b128 patterns bank-balanced
    __shared__ __align__(16) float lin[8 * LST];

    const int t  = threadIdx.x;
    const int nb = t >> 3;
    const int s  = t & 7;
    const int wg = blockIdx.x;

    float* base; unsigned S, BPB, ND; int bid; bool valid;
    if (wg < 1750) { base = b1; S = 80; BPB = 2000; ND = 10; bid = wg*8 + nb; valid = true; }
    else           { base = b2; S = 40; BPB = 250;  ND = 5;  bid = (wg-1750)*8 + nb; valid = bid < 1750; }

    const unsigned S2 = S * S, S3 = S2 * S;
    const unsigned ub   = (unsigned)bid;
    const unsigned band = ub / BPB;
    const unsigned r0   = ub - band * BPB;
    const unsigned nd2  = ND * ND, nd3 = nd2 * ND;
    const unsigned bb   = r0 / nd3;
    const unsigned r1   = r0 - bb * nd3;
    const unsigned di   = r1 / nd2;
    const unsigned r2i  = r1 - di * nd2;
    const unsigned hi   = r2i / ND;
    const unsigned wi   = r2i - hi * ND;
    float* gp = base + (size_t)band * (size_t)(2u * S3) + (size_t)bb * S3
              + (size_t)(8u * di) * S2 + (size_t)(8u * hi) * S + 8u * wi;

    float* L = &lin[nb * LST];

    // ---- stage-in: thread covers rows (i=u, j=s) of its own block ----
    if (valid) {
        #pragma unroll
        for (int u = 0; u < 8; ++u) {
            const float* g0 = gp + u * S2 + s * S;
            float4 v0 = *(const float4*)(g0);
            float4 v1 = *(const float4*)(g0 + 4);
            *(float4*)&L[u*64 + s*8]     = v0;
            *(float4*)&L[u*64 + s*8 + 4] = v1;
        }
    }
    __syncthreads();

    float a[64], g[64], w[64];

    // ---- N0: slice d=s, M[r][c] = blk[s][r][c] ----
    #pragma unroll
    for (int r = 0; r < 8; ++r) {
        float4 v0 = *(const float4*)&L[s*64 + r*8];
        float4 v1 = *(const float4*)&L[s*64 + r*8 + 4];
        a[r*8+0]=v0.x; a[r*8+1]=v0.y; a[r*8+2]=v0.z; a[r*8+3]=v0.w;
        a[r*8+4]=v1.x; a[r*8+5]=v1.y; a[r*8+6]=v1.z; a[r*8+7]=v1.w;
    }
    bandlet_slice(a);

    // ---- N2: M[r][c] = blk[r][c][s]  (strided b32 gather, <=2-way banks) ----
    #pragma unroll
    for (int r = 0; r < 8; ++r)
        #pragma unroll
        for (int c = 0; c < 8; ++c)
            g[r*8+c] = L[r*64 + c*8 + s];
    bandlet_slice(g);   // g = R2 (W-layout), held in regs

    // ---- N1 raw gather: M[r][c] = blk[r][s][c] ----
    #pragma unroll
    for (int r = 0; r < 8; ++r) {
        float4 v0 = *(const float4*)&L[r*64 + s*8];
        float4 v1 = *(const float4*)&L[r*64 + s*8 + 4];
        w[r*8+0]=v0.x; w[r*8+1]=v0.y; w[r*8+2]=v0.z; w[r*8+3]=v0.w;
        w[r*8+4]=v1.x; w[r*8+5]=v1.y; w[r*8+6]=v1.z; w[r*8+7]=v1.w;
    }
    __syncthreads();    // all reads of lin drained -> safe to overwrite

    // ---- scatter R2 to plain positions: element (r,c,s) ----
    #pragma unroll
    for (int r = 0; r < 8; ++r)
        #pragma unroll
        for (int c = 0; c < 8; ++c)
            L[r*64 + c*8 + s] = g[r*8+c];   // g dies here

    bandlet_slice(w);   // w = R1 (H-layout); overlaps the LDS writes above

    __syncthreads();
    // ---- accumulate R2 rows for my slice: element (s, j, k) ----
    #pragma unroll
    for (int r = 0; r < 8; ++r) {
        float4 v0 = *(const float4*)&L[s*64 + r*8];
        float4 v1 = *(const float4*)&L[s*64 + r*8 + 4];
        a[r*8+0]+=v0.x; a[r*8+1]+=v0.y; a[r*8+2]+=v0.z; a[r*8+3]+=v0.w;
        a[r*8+4]+=v1.x; a[r*8+5]+=v1.y; a[r*8+6]+=v1.z; a[r*8+7]+=v1.w;
    }
    __syncthreads();
    // ---- write R1 rows: element (i=r, j=s, k) ----
    #pragma unroll
    for (int r = 0; r < 8; ++r) {
        float4 v0 = make_float4(w[r*8+0], w[r*8+1], w[r*8+2], w[r*8+3]);
        float4 v1 = make_float4(w[r*8+4], w[r*8+5], w[r*8+6], w[r*8+7]);
        *(float4*)&L[r*64 + s*8]     = v0;
        *(float4*)&L[r*64 + s*8 + 4] = v1;
    }
    __syncthreads();
    // ---- accumulate R1 rows for my slice ----
    #pragma unroll
    for (int r = 0; r < 8; ++r) {
        float4 v0 = *(const float4*)&L[s*64 + r*8];
        float4 v1 = *(const float4*)&L[s*64 + r*8 + 4];
        a[r*8+0]+=v0.x; a[r*8+1]+=v0.y; a[r*8+2]+=v0.z; a[r*8+3]+=v0.w;
        a[r*8+4]+=v1.x; a[r*8+5]+=v1.y; a[r*8+6]+=v1.z; a[r*8+7]+=v1.w;
    }

    // ---- stage-out: a/3 to global, slice (s, j, k) ----
    if (valid) {
        #pragma unroll
        for (int j = 0; j < 8; ++j) {
            float4 o0 = make_float4(a[j*8+0]*(1.0f/3.0f), a[j*8+1]*(1.0f/3.0f),
                                    a[j*8+2]*(1.0f/3.0f), a[j*8+3]*(1.0f/3.0f));
            float4 o1 = make_float4(a[j*8+4]*(1.0f/3.0f), a[j*8+5]*(1.0f/3.0f),
                                    a[j*8+6]*(1.0f/3.0f), a[j*8+7]*(1.0f/3.0f));
            float* q = gp + s * S2 + j * S;
            *(float4*)(q)     = o0;
            *(float4*)(q + 4) = o1;
        }
    }
}

// ------------------------------------------------------------------
// Pipeline (5 launches):
//   x (2,1,160^3) --fwd--> bands1[8](2,80^3)   [d_ws]
//   bands1[0]     --fwd--> bands2[8](2,40^3)   [staged in d_out]
//   blockproc2: both levels' bands 1..7 in-place, one dispatch
//   bands2 --inv--> bands1[0] ; bands1 --inv--> d_out
// ------------------------------------------------------------------
extern "C" void kernel_launch(void* const* d_in, const int* in_sizes, int n_in,
                              void* d_out, int out_size, void* d_ws, size_t ws_size,
                              hipStream_t stream) {
    const float* x = (const float*)d_in[0];
    float* out = (float*)d_out;
    float* bands1 = (float*)d_ws;
    float* bands2 = (float*)d_out;

    constexpr int B = 2;
    constexpr size_t B1S = (size_t)B * 80 * 80 * 80;
    constexpr size_t B2S = (size_t)B * 40 * 40 * 40;

    dwt3_fwd<80, B><<<(B*80*80*80) / 256, 256, 0, stream>>>(x, bands1);
    dwt3_fwd<40, B><<<(B*40*40*40) / 256, 256, 0, stream>>>(bands1, bands2);
    blockproc2<<<1750 + 219, 64, 0, stream>>>(bands1 + B1S, bands2 + B2S);
    dwt3_inv<40, B><<<(B*40*40*40) / 256, 256, 0, stream>>>(bands2, bands1);
    dwt3_inv<80, B><<<(B*80*80*80) / 256, 256, 0, stream>>>(bands1, out);
}

// Round 4
// 117.095 us; speedup vs baseline: 1.3075x; 1.0180x over previous
//
#include <hip/hip_runtime.h>

#define IS2 0.7071067811865476f
#define C3F 0.35355339059327373f   // (1/sqrt(2))^3
#define TAU_F 0.05f

// ------------------------------------------------------------------
// 2D multilevel Haar (8x8), matches reference _haar2_fwd / _haar2_inv
// ------------------------------------------------------------------
__device__ __forceinline__ void haar2_fwd(float (&m)[64]) {
    float t[64];
    #pragma unroll
    for (int half = 4; half >= 1; half >>= 1) {
        const int sz = half * 2;
        #pragma unroll
        for (int r = 0; r < half; ++r)
            #pragma unroll
            for (int c = 0; c < sz; ++c) {
                float a = m[(2*r)*8 + c], b = m[(2*r+1)*8 + c];
                t[r*8 + c]        = (a + b) * IS2;
                t[(r+half)*8 + c] = (a - b) * IS2;
            }
        #pragma unroll
        for (int r = 0; r < sz; ++r)
            #pragma unroll
            for (int c = 0; c < sz; ++c) m[r*8+c] = t[r*8+c];
        #pragma unroll
        for (int r = 0; r < sz; ++r)
            #pragma unroll
            for (int c = 0; c < half; ++c) {
                float a = m[r*8 + 2*c], b = m[r*8 + 2*c + 1];
                t[r*8 + c]        = (a + b) * IS2;
                t[r*8 + c + half] = (a - b) * IS2;
            }
        #pragma unroll
        for (int r = 0; r < sz; ++r)
            #pragma unroll
            for (int c = 0; c < sz; ++c) m[r*8+c] = t[r*8+c];
    }
}

__device__ __forceinline__ void haar2_inv(float (&m)[64]) {
    float t[64];
    #pragma unroll
    for (int sz = 2; sz <= 8; sz <<= 1) {
        const int half = sz >> 1;
        #pragma unroll
        for (int r = 0; r < sz; ++r)
            #pragma unroll
            for (int c = 0; c < half; ++c) {
                float lo = m[r*8 + c], hi = m[r*8 + c + half];
                t[r*8 + 2*c]     = (lo + hi) * IS2;
                t[r*8 + 2*c + 1] = (lo - hi) * IS2;
            }
        #pragma unroll
        for (int r = 0; r < sz; ++r)
            #pragma unroll
            for (int c = 0; c < sz; ++c) m[r*8+c] = t[r*8+c];
        #pragma unroll
        for (int r = 0; r < half; ++r)
            #pragma unroll
            for (int c = 0; c < sz; ++c) {
                float lo = m[r*8 + c], hi = m[(r+half)*8 + c];
                t[(2*r)*8 + c]   = (lo + hi) * IS2;
                t[(2*r+1)*8 + c] = (lo - hi) * IS2;
            }
        #pragma unroll
        for (int r = 0; r < sz; ++r)
            #pragma unroll
            for (int c = 0; c < sz; ++c) m[r*8+c] = t[r*8+c];
    }
}

// fwd -> soft-threshold (keep DC) -> inv on one 8x8 slice, in registers
__device__ __forceinline__ void bandlet_slice(float (&m)[64]) {
    haar2_fwd(m);
    float dc = m[0];
    #pragma unroll
    for (int e = 0; e < 64; ++e) {
        float v = m[e];
        float av = fabsf(v) - TAU_F;
        m[e] = av > 0.0f ? copysignf(av, v) : 0.0f;
    }
    m[0] = dc;
    haar2_inv(m);
}

// ------------------------------------------------------------------
// Bandlet core on one 8x8x8 LDS block, PLAIN layout:
//   element (i,j,k) at L[i*64 + j*8 + k], block stride 516 dwords.
// (Verified access pattern from round 2: b128 ops land 8 dwords/bank
//  uniform; b32 ops are 2-way = free.)
// Thread owning slice s ends with a[64] = sum of the 3 normal
// reconstructions for its output slice d=s (NOT yet /3).
// Must be called by ALL threads (barriers inside); invalid threads
// pass valid=false and a safe dummy L.
// ------------------------------------------------------------------
__device__ __forceinline__ void bandlet_core(float* __restrict__ L, int s,
                                             bool valid, float (&a)[64]) {
    float g[64], w[64];
    if (valid) {
        // N0: M[r][c] = blk[s][r][c]
        #pragma unroll
        for (int r = 0; r < 8; ++r) {
            float4 v0 = *(const float4*)&L[s*64 + r*8];
            float4 v1 = *(const float4*)&L[s*64 + r*8 + 4];
            a[r*8+0]=v0.x; a[r*8+1]=v0.y; a[r*8+2]=v0.z; a[r*8+3]=v0.w;
            a[r*8+4]=v1.x; a[r*8+5]=v1.y; a[r*8+6]=v1.z; a[r*8+7]=v1.w;
        }
        bandlet_slice(a);
        // N2: M[r][c] = blk[r][c][s]  (b32, uniform 2-way banks)
        #pragma unroll
        for (int r = 0; r < 8; ++r)
            #pragma unroll
            for (int c = 0; c < 8; ++c)
                g[r*8+c] = L[r*64 + c*8 + s];
        bandlet_slice(g);   // g = R2 result in W-slice layout
        // N1 raw gather: M[r][c] = blk[r][s][c]
        #pragma unroll
        for (int r = 0; r < 8; ++r) {
            float4 v0 = *(const float4*)&L[r*64 + s*8];
            float4 v1 = *(const float4*)&L[r*64 + s*8 + 4];
            w[r*8+0]=v0.x; w[r*8+1]=v0.y; w[r*8+2]=v0.z; w[r*8+3]=v0.w;
            w[r*8+4]=v1.x; w[r*8+5]=v1.y; w[r*8+6]=v1.z; w[r*8+7]=v1.w;
        }
    }
    __syncthreads();    // all reads of L drained -> safe to overwrite
    if (valid) {
        // scatter R2 to element positions (r,c,s)
        #pragma unroll
        for (int r = 0; r < 8; ++r)
            #pragma unroll
            for (int c = 0; c < 8; ++c)
                L[r*64 + c*8 + s] = g[r*8+c];
        bandlet_slice(w);   // R1, overlaps the LDS writes above
    }
    __syncthreads();
    if (valid) {
        // accumulate R2 rows of my slice (s, j, k)
        #pragma unroll
        for (int r = 0; r < 8; ++r) {
            float4 v0 = *(const float4*)&L[s*64 + r*8];
            float4 v1 = *(const float4*)&L[s*64 + r*8 + 4];
            a[r*8+0]+=v0.x; a[r*8+1]+=v0.y; a[r*8+2]+=v0.z; a[r*8+3]+=v0.w;
            a[r*8+4]+=v1.x; a[r*8+5]+=v1.y; a[r*8+6]+=v1.z; a[r*8+7]+=v1.w;
        }
    }
    __syncthreads();
    if (valid) {
        // write R1 rows (i=r, j=s, k)
        #pragma unroll
        for (int r = 0; r < 8; ++r) {
            *(float4*)&L[r*64 + s*8]     = make_float4(w[r*8+0], w[r*8+1], w[r*8+2], w[r*8+3]);
            *(float4*)&L[r*64 + s*8 + 4] = make_float4(w[r*8+4], w[r*8+5], w[r*8+6], w[r*8+7]);
        }
    }
    __syncthreads();
    if (valid) {
        // accumulate R1 rows of my slice
        #pragma unroll
        for (int r = 0; r < 8; ++r) {
            float4 v0 = *(const float4*)&L[s*64 + r*8];
            float4 v1 = *(const float4*)&L[s*64 + r*8 + 4];
            a[r*8+0]+=v0.x; a[r*8+1]+=v0.y; a[r*8+2]+=v0.z; a[r*8+3]+=v0.w;
            a[r*8+4]+=v1.x; a[r*8+5]+=v1.y; a[r*8+6]+=v1.z; a[r*8+7]+=v1.w;
        }
    }
}

// ------------------------------------------------------------------
// Kernel A: fused level-1 forward DWT + level-1 blockproc.
// One wg (64 thr) = one 16^3 input tile -> one 8^3 block of each of
// the 7 H-bands (processed in LDS) + lll written raw to bands[0].
// Grid: 2 * 10^3 = 2000 wgs. PLAIN LDS layout.
// ------------------------------------------------------------------
__global__ __launch_bounds__(64, 2) void fwd1_bp(const float* __restrict__ x,
                                                 float* __restrict__ bands) {
    constexpr int LST = 516;
    constexpr size_t B1S = (size_t)2 * 80 * 80 * 80;
    __shared__ __align__(16) float lin[7 * LST];

    const int t  = threadIdx.x;
    const int wg = blockIdx.x;
    const int b  = wg / 1000;
    const int tl = wg - b * 1000;
    const int td = tl / 100;
    const int rr = tl - td * 100;
    const int th = rr / 10;
    const int tw = rr - th * 10;
    const int j = t >> 3, w = t & 7;

    const float* ip = x + ((size_t)(b*160 + 16*td)) * 25600 + (size_t)(16*th) * 160 + 16*tw;
    float* lllp = bands + ((size_t)(b*80 + 8*td)) * 6400 + (size_t)(8*th) * 80 + 8*tw;

    // ---- phase 1: level-1 forward, voxel (d=q, h=j, w=w) of the tile ----
    #pragma unroll
    for (int q = 0; q < 8; ++q) {
        const float* p = ip + (size_t)(2*q) * 25600 + (2*j) * 160 + 2*w;
        float2 q00 = *(const float2*)(p);
        float2 q01 = *(const float2*)(p + 160);
        float2 q10 = *(const float2*)(p + 25600);
        float2 q11 = *(const float2*)(p + 25600 + 160);
        float wl00 = q00.x + q00.y, wh00 = q00.x - q00.y;
        float wl01 = q01.x + q01.y, wh01 = q01.x - q01.y;
        float wl10 = q10.x + q10.y, wh10 = q10.x - q10.y;
        float wl11 = q11.x + q11.y, wh11 = q11.x - q11.y;
        float hl0l = wl00 + wl01, hh0l = wl00 - wl01;
        float hl0h = wh00 + wh01, hh0h = wh00 - wh01;
        float hl1l = wl10 + wl11, hh1l = wl10 - wl11;
        float hl1h = wh10 + wh11, hh1h = wh10 - wh11;
        const int pos = q*64 + j*8 + w;               // PLAIN layout
        lin[0*LST + pos] = (hl0h + hl1h) * C3F;   // band 1 llh
        lin[1*LST + pos] = (hh0l + hh1l) * C3F;   // band 2 lhl
        lin[2*LST + pos] = (hh0h + hh1h) * C3F;   // band 3 lhh
        lin[3*LST + pos] = (hl0l - hl1l) * C3F;   // band 4 hll
        lin[4*LST + pos] = (hl0h - hl1h) * C3F;   // band 5 hlh
        lin[5*LST + pos] = (hh0l - hh1l) * C3F;   // band 6 hhl
        lin[6*LST + pos] = (hh0h - hh1h) * C3F;   // band 7 hhh
        lllp[q*6400 + j*80 + w] = (hl0l + hl1l) * C3F;   // band 0 lll (raw)
    }
    __syncthreads();

    // ---- phase 2: blockproc the 7 band blocks ----
    const int nbp = t >> 3, s = t & 7;
    const bool valid = nbp < 7;
    float a[64];
    bandlet_core(&lin[(valid ? nbp : 0) * LST], s, valid, a);

    // ---- phase 3: stage-out processed band (nbp+1), slice d=s ----
    if (valid) {
        float* gp = bands + (size_t)(nbp + 1) * B1S
                  + ((size_t)(b*80 + 8*td + s)) * 6400 + (size_t)(8*th) * 80 + 8*tw;
        #pragma unroll
        for (int jj = 0; jj < 8; ++jj) {
            float* qo = gp + jj * 80;
            *(float4*)(qo)     = make_float4(a[jj*8+0]*(1.0f/3.0f), a[jj*8+1]*(1.0f/3.0f),
                                             a[jj*8+2]*(1.0f/3.0f), a[jj*8+3]*(1.0f/3.0f));
            *(float4*)(qo + 4) = make_float4(a[jj*8+4]*(1.0f/3.0f), a[jj*8+5]*(1.0f/3.0f),
                                             a[jj*8+6]*(1.0f/3.0f), a[jj*8+7]*(1.0f/3.0f));
        }
    }
}

// ------------------------------------------------------------------
// Kernel B: fused level-2 forward + blockproc + level-2 inverse,
// in place on lll1 (= bands[0], shape (2,80,80,80)).
// One wg = one 16^3 tile of lll1. Grid: 2 * 5^3 = 250 wgs.
// Level-2 band data never touches global memory. PLAIN LDS layout.
// ------------------------------------------------------------------
__global__ __launch_bounds__(64, 2) void l2_pipeline(float* __restrict__ lll) {
    constexpr int LST = 516;
    __shared__ __align__(16) float lin[8 * LST];

    const int t  = threadIdx.x;
    const int wg = blockIdx.x;
    const int b  = wg / 125;
    const int tl = wg - b * 125;
    const int td = tl / 25;
    const int rr = tl - td * 25;
    const int th = rr / 5;
    const int tw = rr - th * 5;
    const int j = t >> 3, w = t & 7;

    float* base = lll + ((size_t)(b*80 + 16*td)) * 6400 + (size_t)(16*th) * 80 + 16*tw;

    // ---- phase 1: level-2 forward, all 8 bands into LDS ----
    #pragma unroll
    for (int q = 0; q < 8; ++q) {
        const float* p = base + (size_t)(2*q) * 6400 + (2*j) * 80 + 2*w;
        float2 q00 = *(const float2*)(p);
        float2 q01 = *(const float2*)(p + 80);
        float2 q10 = *(const float2*)(p + 6400);
        float2 q11 = *(const float2*)(p + 6400 + 80);
        float wl00 = q00.x + q00.y, wh00 = q00.x - q00.y;
        float wl01 = q01.x + q01.y, wh01 = q01.x - q01.y;
        float wl10 = q10.x + q10.y, wh10 = q10.x - q10.y;
        float wl11 = q11.x + q11.y, wh11 = q11.x - q11.y;
        float hl0l = wl00 + wl01, hh0l = wl00 - wl01;
        float hl0h = wh00 + wh01, hh0h = wh00 - wh01;
        float hl1l = wl10 + wl11, hh1l = wl10 - wl11;
        float hl1h = wh10 + wh11, hh1h = wh10 - wh11;
        const int pos = q*64 + j*8 + w;               // PLAIN layout
        lin[0*LST + pos] = (hl0l + hl1l) * C3F;   // lll2 (kept unprocessed)
        lin[1*LST + pos] = (hl0h + hl1h) * C3F;
        lin[2*LST + pos] = (hh0l + hh1l) * C3F;
        lin[3*LST + pos] = (hh0h + hh1h) * C3F;
        lin[4*LST + pos] = (hl0l - hl1l) * C3F;
        lin[5*LST + pos] = (hl0h - hl1h) * C3F;
        lin[6*LST + pos] = (hh0l - hh1l) * C3F;
        lin[7*LST + pos] = (hh0h - hh1h) * C3F;
    }
    __syncthreads();

    // ---- phase 2: blockproc bands 1..7 (buffer 0 = lll2 untouched) ----
    const int nbp = t >> 3, s = t & 7;
    const bool valid = nbp < 7;
    float a[64];
    bandlet_core(&lin[(valid ? nbp + 1 : 0) * LST], s, valid, a);

    __syncthreads();   // core's last reads drained before write-back
    if (valid) {
        float* L = &lin[(nbp + 1) * LST];
        #pragma unroll
        for (int jj = 0; jj < 8; ++jj) {
            *(float4*)&L[s*64 + jj*8]     = make_float4(a[jj*8+0]*(1.0f/3.0f), a[jj*8+1]*(1.0f/3.0f),
                                                        a[jj*8+2]*(1.0f/3.0f), a[jj*8+3]*(1.0f/3.0f));
            *(float4*)&L[s*64 + jj*8 + 4] = make_float4(a[jj*8+4]*(1.0f/3.0f), a[jj*8+5]*(1.0f/3.0f),
                                                        a[jj*8+6]*(1.0f/3.0f), a[jj*8+7]*(1.0f/3.0f));
        }
    }
    __syncthreads();

    // ---- phase 3: level-2 inverse, write back in place ----
    #pragma unroll
    for (int q = 0; q < 8; ++q) {
        const int pos = q*64 + j*8 + w;               // PLAIN layout
        float b0 = lin[0*LST + pos], b1 = lin[1*LST + pos];
        float b2 = lin[2*LST + pos], b3 = lin[3*LST + pos];
        float b4 = lin[4*LST + pos], b5 = lin[5*LST + pos];
        float b6 = lin[6*LST + pos], b7 = lin[7*LST + pos];
        float c0 = b0 + b4, c1 = b1 + b5, c2 = b2 + b6, c3 = b3 + b7;
        float c4 = b0 - b4, c5 = b1 - b5, c6 = b2 - b6, c7 = b3 - b7;
        float e00 = c0 + c2, e01 = c1 + c3;
        float e02 = c0 - c2, e03 = c1 - c3;
        float e10 = c4 + c6, e11 = c5 + c7;
        float e12 = c4 - c6, e13 = c5 - c7;
        float* pp = base + (size_t)(2*q) * 6400 + (2*j) * 80 + 2*w;
        *(float2*)(pp)             = make_float2((e00+e01)*C3F, (e00-e01)*C3F);
        *(float2*)(pp + 80)        = make_float2((e02+e03)*C3F, (e02-e03)*C3F);
        *(float2*)(pp + 6400)      = make_float2((e10+e11)*C3F, (e10-e11)*C3F);
        *(float2*)(pp + 6400 + 80) = make_float2((e12+e13)*C3F, (e12-e13)*C3F);
    }
}

// ------------------------------------------------------------------
// Kernel C: level-1 inverse, 8 bands (2,80^3) -> out (2,160^3)
// ------------------------------------------------------------------
__global__ __launch_bounds__(256) void dwt3_inv80(const float* __restrict__ bands,
                                                  float* __restrict__ out) {
    const int tid = blockIdx.x * blockDim.x + threadIdx.x;
    constexpr int S = 80;
    const int w = tid % S;
    const int h = (tid / S) % S;
    const int d = (tid / (S*S)) % S;
    const int b = tid / (S*S*S);
    constexpr size_t bs_ = (size_t)2 * S * S * S;
    const size_t o = (size_t)tid;

    float b0 = bands[0*bs_+o], b1 = bands[1*bs_+o], b2 = bands[2*bs_+o], b3 = bands[3*bs_+o];
    float b4 = bands[4*bs_+o], b5 = bands[5*bs_+o], b6 = bands[6*bs_+o], b7 = bands[7*bs_+o];
    float c0 = b0 + b4, c1 = b1 + b5, c2 = b2 + b6, c3 = b3 + b7;
    float c4 = b0 - b4, c5 = b1 - b5, c6 = b2 - b6, c7 = b3 - b7;
    float e00 = c0 + c2, e01 = c1 + c3;
    float e02 = c0 - c2, e03 = c1 - c3;
    float e10 = c4 + c6, e11 = c5 + c7;
    float e12 = c4 - c6, e13 = c5 - c7;
    constexpr int IS = 2 * S;
    float* p = out + (((size_t)b * IS + 2*d) * IS + 2*h) * IS + 2*w;
    *(float2*)(p)                      = make_float2((e00+e01)*C3F, (e00-e01)*C3F);
    *(float2*)(p + IS)                 = make_float2((e02+e03)*C3F, (e02-e03)*C3F);
    *(float2*)(p + (size_t)IS*IS)      = make_float2((e10+e11)*C3F, (e10-e11)*C3F);
    *(float2*)(p + (size_t)IS*IS + IS) = make_float2((e12+e13)*C3F, (e12-e13)*C3F);
}

// ------------------------------------------------------------------
// Pipeline (3 launches):
//   A: x (2,160^3) -> bands[0]=lll1 raw, bands[1..7] processed   [d_ws]
//   B: bands[0] -> fwd2 + blockproc + inv2, in place (LDS-resident)
//   C: bands[0..7] -> inverse level-1 -> d_out
// ------------------------------------------------------------------
extern "C" void kernel_launch(void* const* d_in, const int* in_sizes, int n_in,
                              void* d_out, int out_size, void* d_ws, size_t ws_size,
                              hipStream_t stream) {
    const float* x = (const float*)d_in[0];
    float* out = (float*)d_out;
    float* bands = (float*)d_ws;   // 8 * 2*80^3 floats = 32.77 MB

    fwd1_bp<<<2000, 64, 0, stream>>>(x, bands);
    l2_pipeline<<<250, 64, 0, stream>>>(bands);
    dwt3_inv80<<<4000, 256, 0, stream>>>(bands, out);
}